// Round 3
// baseline (244.100 us; speedup 1.0000x reference)
//
#include <hip/hip_runtime.h>

// Problem constants (from reference):
//   x: [B=32, C=1, F=257, T=4096] float32 log-magnitude spectrogram
//   SHIFT_BINS = 20.0 / (16000/512) = 0.64  -> f_low = f, f_high = f+1
//   out[b,f,t] = log10((1-a)*10^x[b,f,t] + a*10^x[b,f+1,t] + 1e-8), f < 256
//   out[b,256,t] = log10(1e-8)   (valid mask false at the top bin)
//
// Round 3 structure: software-pipelined row-tasks. Each block owns TASKS=4
// consecutive (b,f) rows; loads for task t+1 are issued BEFORE task t's
// transcendental chain, so 8 global_load_dwordx4 stay in flight across the
// compute phase (counted-vmcnt pattern). R0-R2 alternated
// all-loads / all-compute phases -> memory pipe idle ~50% -> 3.3 TB/s.
#define B_DIM 32
#define F_DIM 257
#define T_DIM 4096
#define EPS_F 1e-8f

#define LOG2_10  3.32192809488736234787f
#define LOG10_2  0.30102999566398119521f

#define TASKS 4                          // row-tasks per block
#define NBLK  (B_DIM * F_DIM / TASKS)    // 8224/4 = 2056 blocks
#define ROWV  (T_DIM / 4)                // 1024 f32x4 per row
#define XCD_CHUNK (NBLK / 8)             // 257; bijective since NBLK % 8 == 0

typedef float f32x4 __attribute__((ext_vector_type(4)));

__device__ __forceinline__ float pow10_fast(float v) {
    // 10^v = 2^(v * log2(10)); v_exp_f32 is ~1 ulp — far under the absmax threshold
    return __builtin_amdgcn_exp2f(v * LOG2_10);
}
__device__ __forceinline__ float log10_fast(float v) {
    return __builtin_amdgcn_logf(v) * LOG10_2;  // v_log_f32 is log2
}

__global__ __launch_bounds__(256) void freq_shift_kernel(
        const float* __restrict__ x, float* __restrict__ out) {
    const int tid = threadIdx.x;
    // XCD-chunked bijective swizzle: neighbor blocks (sharing a boundary row)
    // land on the same XCD's L2.
    const int bid = blockIdx.x;
    const int id  = (bid & 7) * XCD_CHUNK + (bid >> 3);
    const int t0  = id * TASKS;          // first (b*F + f) row-task of this block

    // Double-buffered register staging: 2 x (4+4) f32x4.
    f32x4 va[2][4], vb[2][4];

    auto issue = [&](int task) {
        const int bf = t0 + task;
        const int f  = bf % F_DIM;
        const long long base = (long long)bf * T_DIM;
        const f32x4* __restrict__ r0 = (const f32x4*)(x + base);
        // top bin has no f+1 row (next b's f=0 would be wrong; last one OOB):
        // load row f twice, result is overridden by the constant path anyway.
        const f32x4* __restrict__ r1 = (f == F_DIM - 1) ? r0 : r0 + ROWV;
        const int buf = task & 1;
#pragma unroll
        for (int i = 0; i < 4; ++i) va[buf][i] = r0[i * 256 + tid];
#pragma unroll
        for (int i = 0; i < 4; ++i) vb[buf][i] = r1[i * 256 + tid];
    };

    issue(0);                            // pipeline prologue
#pragma unroll
    for (int t = 0; t < TASKS; ++t) {
        if (t + 1 < TASKS) issue(t + 1); // loads in flight across compute below

        const int bf = t0 + t;
        const int f  = bf % F_DIM;
        f32x4* __restrict__ orow = (f32x4*)(out + (long long)bf * T_DIM);

        if (f == F_DIM - 1) {
            // invalid top bin: log10(0 + 1e-8); block-uniform branch
            const float cv = log10_fast(EPS_F);
            f32x4 v; v.x = cv; v.y = cv; v.z = cv; v.w = cv;
#pragma unroll
            for (int i = 0; i < 4; ++i)
                __builtin_nontemporal_store(v, orow + i * 256 + tid);
            continue;
        }

        // Reproduce reference fp32 alpha: target = fl(f + 0.64f); alpha = target - f
        // (exact subtraction by Sterbenz; matches jnp float32 weak-typed arithmetic)
        const float ff    = (float)f;
        const float alpha = (ff + 0.64f) - ff;
        const float beta  = 1.0f - alpha;
        const int   buf   = t & 1;

#pragma unroll
        for (int i = 0; i < 4; ++i) {
            const f32x4 a = va[buf][i];
            const f32x4 b = vb[buf][i];
            f32x4 r;
            r.x = log10_fast(beta * pow10_fast(a.x) + alpha * pow10_fast(b.x) + EPS_F);
            r.y = log10_fast(beta * pow10_fast(a.y) + alpha * pow10_fast(b.y) + EPS_F);
            r.z = log10_fast(beta * pow10_fast(a.z) + alpha * pow10_fast(b.z) + EPS_F);
            r.w = log10_fast(beta * pow10_fast(a.w) + alpha * pow10_fast(b.w) + EPS_F);
            // out is write-once, never re-read: nontemporal store keeps L2
            // lines free for the shared boundary-row reads.
            __builtin_nontemporal_store(r, orow + i * 256 + tid);
        }
    }
}

extern "C" void kernel_launch(void* const* d_in, const int* in_sizes, int n_in,
                              void* d_out, int out_size, void* d_ws, size_t ws_size,
                              hipStream_t stream) {
    const float* x = (const float*)d_in[0];
    float* out = (float*)d_out;
    // 2056 blocks x 256 threads; each block pipelines 4 consecutive rows.
    dim3 grid(NBLK);
    dim3 block(256);
    freq_shift_kernel<<<grid, block, 0, stream>>>(x, out);
}

// Round 4
// 224.929 us; speedup vs baseline: 1.0852x; 1.0852x over previous
//
#include <hip/hip_runtime.h>

// Problem constants (from reference):
//   x: [B=32, C=1, F=257, T=4096] float32 log-magnitude spectrogram
//   SHIFT_BINS = 20.0 / (16000/512) = 0.64  -> f_low = f, f_high = f+1
//   out[b,f,t] = log10((1-a)*10^x[b,f,t] + a*10^x[b,f+1,t] + 1e-8), f < 256
//   out[b,256,t] = log10(1e-8)   (valid mask false at the top bin)
//
// Round 4: same structure as the best-measured variant (R1: one row-pair per
// block), but the load staging is FORCED into the binary with
// __builtin_amdgcn_sched_barrier(0). R1-R3 post-mortem: VGPR_Count (24/36/36)
// proved hipcc sank every "staged" load back to its use, so only ~2 loads were
// ever in flight per wave — the MLP experiments never existed in the binary.
// The barrier pins all 8 global_load_dwordx4 (128 B/thread) before compute.
#define B_DIM 32
#define F_DIM 257
#define T_DIM 4096
#define EPS_F 1e-8f

#define LOG2_10  3.32192809488736234787f
#define LOG10_2  0.30102999566398119521f

typedef float f32x4 __attribute__((ext_vector_type(4)));

__device__ __forceinline__ float pow10_fast(float v) {
    // 10^v = 2^(v * log2(10)); v_exp_f32 is ~1 ulp — far under the absmax threshold
    return __builtin_amdgcn_exp2f(v * LOG2_10);
}
__device__ __forceinline__ float log10_fast(float v) {
    return __builtin_amdgcn_logf(v) * LOG10_2;  // v_log_f32 is log2
}

__global__ __launch_bounds__(256) void freq_shift_kernel(
        const float* __restrict__ x, float* __restrict__ out) {
    const int bf = blockIdx.x;            // flattened (b*F + f); rows are contiguous
    const int f  = bf % F_DIM;
    const long long base = (long long)bf * T_DIM;
    const int tid = threadIdx.x;

    f32x4* __restrict__ orow = (f32x4*)(out + base);

    if (f == F_DIM - 1) {
        // invalid top bin: log10(0 + 1e-8); block-uniform branch, no divergence
        const float cv = log10_fast(EPS_F);
        f32x4 v; v.x = cv; v.y = cv; v.z = cv; v.w = cv;
#pragma unroll
        for (int i = 0; i < T_DIM / 4 / 256; ++i)
            __builtin_nontemporal_store(v, orow + i * 256 + tid);
        return;
    }

    const f32x4* __restrict__ row0 = (const f32x4*)(x + base);
    const f32x4* __restrict__ row1 = (const f32x4*)(x + base + T_DIM);

    // Reproduce reference fp32 alpha: target = fl(f + 0.64f); alpha = target - f
    // (exact subtraction by Sterbenz; matches jnp float32 weak-typed arithmetic)
    const float ff     = (float)f;
    const float target = ff + 0.64f;
    const float alpha  = target - ff;
    const float beta   = 1.0f - alpha;

    // Issue ALL 8 loads, in (va[i], vb[i]) pair order so the first compute
    // iteration's operands are the OLDEST outstanding loads: the compiler can
    // then start compute 0 at s_waitcnt vmcnt(6) with 6 loads still in flight.
    f32x4 va[4], vb[4];
#pragma unroll
    for (int i = 0; i < 4; ++i) {
        va[i] = row0[i * 256 + tid];
        vb[i] = row1[i * 256 + tid];
    }
    // Fence: nothing (in particular, no load) may be moved across this point.
    // This is what R1 was missing — without it hipcc sinks loads to their uses.
    __builtin_amdgcn_sched_barrier(0);

#pragma unroll
    for (int i = 0; i < 4; ++i) {
        f32x4 r;
        r.x = log10_fast(beta * pow10_fast(va[i].x) + alpha * pow10_fast(vb[i].x) + EPS_F);
        r.y = log10_fast(beta * pow10_fast(va[i].y) + alpha * pow10_fast(vb[i].y) + EPS_F);
        r.z = log10_fast(beta * pow10_fast(va[i].z) + alpha * pow10_fast(vb[i].z) + EPS_F);
        r.w = log10_fast(beta * pow10_fast(va[i].w) + alpha * pow10_fast(vb[i].w) + EPS_F);
        // out is write-once, never re-read: nontemporal store keeps cache lines
        // free for the row f+1 re-read dedup.
        __builtin_nontemporal_store(r, orow + i * 256 + tid);
    }
}

extern "C" void kernel_launch(void* const* d_in, const int* in_sizes, int n_in,
                              void* d_out, int out_size, void* d_ws, size_t ws_size,
                              hipStream_t stream) {
    const float* x = (const float*)d_in[0];
    float* out = (float*)d_out;
    // grid: one block per (b,f) row; 32*257 = 8224 blocks, 256 threads,
    // 4 float4 iterations per thread covering T=4096
    dim3 grid(B_DIM * F_DIM);
    dim3 block(256);
    freq_shift_kernel<<<grid, block, 0, stream>>>(x, out);
}